// Round 7
// baseline (398.936 us; speedup 1.0000x reference)
//
#include <hip/hip_runtime.h>
#include <hip/hip_bf16.h>

#define NB   8
#define NS   5
#define NQ   128
#define TT   16
#define DD   2048
#define NROW 1024               // B*nq
#define NSROW (NB * NS * TT)    // 640 supp rows
#define KS   4                  // K-split factor (blocks per (b,q))
#define KSTEPS 16               // k-steps of 32 per slice (DD/32/KS)
#define LAMI 10.0f
#define LAMF 0.1f

typedef __attribute__((ext_vector_type(8))) short  short8;
typedef __attribute__((ext_vector_type(4))) float  float4v;

// pack two f32 -> bf16x2 (RNE)
static __device__ __forceinline__ unsigned int f2bf2(float x, float y) {
    union { float f; unsigned int u; } a, b; a.f = x; b.f = y;
    unsigned int ra = a.u + 0x7fffu + ((a.u >> 16) & 1u);
    unsigned int rb = b.u + 0x7fffu + ((b.u >> 16) & 1u);
    return (ra >> 16) | (rb & 0xffff0000u);
}

static __device__ __forceinline__ float lse2f(float x, float y) {
    float mx = fmaxf(x, y), mn = fminf(x, y);
    return mx + __logf(1.0f + __expf(mn - mx));
}

// supp only: f32 -> bf16 + row sum-of-squares. One wave per row (640 rows).
__global__ __launch_bounds__(256) void
preproc_supp(const float* __restrict__ supp, unsigned short* __restrict__ suppBf,
             float* __restrict__ suppSq)
{
    const int wave = threadIdx.x >> 6, lane = threadIdx.x & 63;
    const int row = blockIdx.x * 4 + wave;           // 0..639
    const float* src = supp + (size_t)row * DD;
    unsigned short* dst = suppBf + (size_t)row * DD;
    float ss = 0.f;
    #pragma unroll
    for (int i = 0; i < 8; ++i) {
        float4 v = *reinterpret_cast<const float4*>(src + i * 256 + lane * 4);
        uint2 pv = { f2bf2(v.x, v.y), f2bf2(v.z, v.w) };
        *reinterpret_cast<uint2*>(dst + i * 256 + lane * 4) = pv;
        ss += v.x * v.x + v.y * v.y + v.z * v.z + v.w * v.w;
    }
    #pragma unroll
    for (int off = 32; off >= 1; off >>= 1) ss += __shfl_xor(ss, off, 64);
    if (lane == 0) suppSq[row] = ss;
}

// ---- kernel B: partial GEMM, K split across blocks ----
// grid = NROW*KS; block (blk, ks) computes, for all 5 supports, the partial dot tile
// over K slice [ks*512, (ks+1)*512). Wave = support s. Query slice is loaded by all
// 5 waves (same addresses -> L1); A from L2-hot suppBf. Hand-unrolled 4-step chunk
// double-buffer with literal indices (spill-proof). Partials stored plain to ws.

#define LOADSTEP(pre, slot, kstep)                                              \
    pre##q0[slot] = *reinterpret_cast<const float4*>(qp + (kstep) * 32);        \
    pre##q1[slot] = *reinterpret_cast<const float4*>(qp + (kstep) * 32 + 4);    \
    pre##a[slot]  = *reinterpret_cast<const short8*>(ap + (kstep) * 32);

#define PROCSTEP(pre, slot) {                                                   \
    float4 v0 = pre##q0[slot], v1 = pre##q1[slot];                              \
    union { short8 s8; unsigned int u[4]; } bu;                                 \
    bu.u[0] = f2bf2(v0.x, v0.y);                                                \
    bu.u[1] = f2bf2(v0.z, v0.w);                                                \
    bu.u[2] = f2bf2(v1.x, v1.y);                                                \
    bu.u[3] = f2bf2(v1.z, v1.w);                                                \
    qss += v0.x * v0.x + v0.y * v0.y + v0.z * v0.z + v0.w * v0.w               \
         + v1.x * v1.x + v1.y * v1.y + v1.z * v1.z + v1.w * v1.w;              \
    acc = __builtin_amdgcn_mfma_f32_16x16x32_bf16(pre##a[slot], bu.s8, acc, 0, 0, 0); }

__global__ __launch_bounds__(320, 4) void
partial_gemm_kernel(const unsigned short* __restrict__ suppBf, const float* __restrict__ query,
                    float* __restrict__ dotBuf, float* __restrict__ qssBuf)
{
    const int tid  = threadIdx.x;
    const int blk  = blockIdx.x >> 2;     // (b,q) 0..1023
    const int ks   = blockIdx.x & 3;      // K-slice 0..3
    const int wave = tid >> 6;            // 0..4 == s
    const int lane = tid & 63;
    const int fr   = lane & 15;
    const int quad = lane >> 4;

    const float* qp = query + ((size_t)(blk * TT + fr)) * DD + ks * (KSTEPS * 32) + quad * 8;
    const unsigned short* ap =
        suppBf + ((size_t)((blk >> 7) * NS + wave) * TT + fr) * DD + ks * (KSTEPS * 32) + quad * 8;

    float4 Aq0[4], Aq1[4], Bq0[4], Bq1[4];
    short8 Aa[4], Ba[4];
    float4v acc = {0.f, 0.f, 0.f, 0.f};
    float qss = 0.f;

    // chunk 0 -> A
    LOADSTEP(A, 0, 0)  LOADSTEP(A, 1, 1)  LOADSTEP(A, 2, 2)  LOADSTEP(A, 3, 3)
    // load chunk1 -> B, process A
    LOADSTEP(B, 0, 4)  LOADSTEP(B, 1, 5)  LOADSTEP(B, 2, 6)  LOADSTEP(B, 3, 7)
    PROCSTEP(A, 0) PROCSTEP(A, 1) PROCSTEP(A, 2) PROCSTEP(A, 3)
    // load chunk2 -> A, process B
    LOADSTEP(A, 0, 8)  LOADSTEP(A, 1, 9)  LOADSTEP(A, 2, 10) LOADSTEP(A, 3, 11)
    PROCSTEP(B, 0) PROCSTEP(B, 1) PROCSTEP(B, 2) PROCSTEP(B, 3)
    // load chunk3 -> B, process A
    LOADSTEP(B, 0, 12) LOADSTEP(B, 1, 13) LOADSTEP(B, 2, 14) LOADSTEP(B, 3, 15)
    PROCSTEP(A, 0) PROCSTEP(A, 1) PROCSTEP(A, 2) PROCSTEP(A, 3)
    // process B
    PROCSTEP(B, 0) PROCSTEP(B, 1) PROCSTEP(B, 2) PROCSTEP(B, 3)

    // store partial dot tile: dotBuf[(ks*1024+blk)*5+s][l][m], C-layout l=quad*4+r, m=fr
    float* dp = dotBuf + (((size_t)(ks * NROW + blk) * NS + wave) * 256);
    #pragma unroll
    for (int r = 0; r < 4; ++r)
        dp[(quad * 4 + r) * 16 + fr] = acc[r];

    // query sumsq partial for this slice (identical in all waves; wave 0 writes)
    qss += __shfl_xor(qss, 16, 64);
    qss += __shfl_xor(qss, 32, 64);
    if (wave == 0 && lane < 16)
        qssBuf[(size_t)(ks * NROW + blk) * 16 + lane] = qss;
}

// ---- kernel C: reduce partials, normalize, DTW ----
__global__ __launch_bounds__(320) void
dtw_kernel(const float* __restrict__ dotBuf, const float* __restrict__ qssBuf,
           const float* __restrict__ suppSq,
           float* __restrict__ out_tam, float* __restrict__ t1w, float* __restrict__ t2w)
{
    __shared__ float ssqS[80];
    __shared__ float ssqQ[16];
    __shared__ float distS[NS][TT][TT];
    __shared__ float tamv[16];

    const int tid  = threadIdx.x;
    const int blk  = blockIdx.x;
    const int wave = tid >> 6;            // 0..4 == s
    const int lane = tid & 63;
    const int fr   = lane & 15;
    const int quad = lane >> 4;

    if (tid < 80) ssqS[tid] = suppSq[(blk >> 7) * (NS * TT) + tid];
    if (tid >= 80 && tid < 96) {
        int m = tid - 80;
        float t = 0.f;
        #pragma unroll
        for (int k = 0; k < KS; ++k) t += qssBuf[(size_t)(k * NROW + blk) * 16 + m];
        ssqQ[m] = sqrtf(t);
    }

    float dot[4];
    {
        const float* dp0 = dotBuf + (((size_t)blk * NS + wave) * 256);
        #pragma unroll
        for (int r = 0; r < 4; ++r) {
            int off = (quad * 4 + r) * 16 + fr;
            float t = 0.f;
            #pragma unroll
            for (int k = 0; k < KS; ++k) t += dp0[(size_t)k * NROW * NS * 256 + off];
            dot[r] = t;
        }
    }
    __syncthreads();

    {
        float qn = ssqQ[fr];
        #pragma unroll
        for (int r = 0; r < 4; ++r) {
            int l = quad * 4 + r;
            float denom = fmaxf(sqrtf(ssqS[wave * 16 + l]) * qn, 1e-8f);
            distS[wave][l][fr] = 1.0f - dot[r] / denom;
        }
    }
    __syncthreads();

    // DTW: anti-diagonal wavefront; wave s, lanes 0..17 dir=0, 32..49 dir=1
    if ((lane & 31) <= 17) {
        const int g   = lane & 31;
        const int dir = lane >> 5;
        const int s   = wave;
        float val = 0.f, vprev = 0.f;
        #pragma unroll
        for (int t = 1; t <= 32; ++t) {
            float left = __shfl_up(val,   1, 32);
            float diag = __shfl_up(vprev, 1, 32);
            int l = t - g;
            if (g >= 1 && l >= 0 && l <= 15) {
                float d = 0.f;
                if (g <= 16) d = dir ? distS[s][15 - l][16 - g] : distS[s][l][g - 1];
                float nv;
                if (l == 0) {
                    nv = left + d;
                } else if (g == 1 || g == 17) {
                    nv = -LAMF * lse2f(lse2f(-diag * LAMI, -left * LAMI), -val * LAMI) + d;
                } else {
                    float lo2 = fminf(diag, left), hi2 = fmaxf(diag, left);
                    nv = lo2 - LAMF * __logf(1.0f + __expf((lo2 - hi2) * LAMI)) + d;
                }
                vprev = val; val = nv;
            }
        }
        if (g == 17) tamv[s * 2 + dir] = val;
    }
    __syncthreads();

    if (tid < NS) {
        float t1 = tamv[2 * tid], t2 = tamv[2 * tid + 1];
        int n = blk * NS + tid;
        t1w[n] = t1;
        t2w[n] = t2;
        out_tam[n] = 0.5f * (t1 + t2);
    }
}

__global__ __launch_bounds__(1024) void
loss_kernel(const float* __restrict__ t1w, const float* __restrict__ t2w,
            const int* __restrict__ ys, float* __restrict__ out)
{
    __shared__ float red[16];
    const int row = threadIdx.x;

    float t1[NS], t2[NS];
    #pragma unroll
    for (int s = 0; s < NS; ++s) { t1[s] = t1w[row * NS + s]; t2[s] = t2w[row * NS + s]; }
    const int y = ys[row];

    float mx1 = -t1[0], mx2 = -t2[0];
    #pragma unroll
    for (int s = 1; s < NS; ++s) { mx1 = fmaxf(mx1, -t1[s]); mx2 = fmaxf(mx2, -t2[s]); }
    float s1 = 0.f, s2 = 0.f;
    #pragma unroll
    for (int s = 0; s < NS; ++s) { s1 += __expf(-t1[s] - mx1); s2 += __expf(-t2[s] - mx2); }
    float lse1  = mx1 + __logf(s1);
    float lse2v = mx2 + __logf(s2);

    float ty1 = t1[0], ty2 = t2[0];
    #pragma unroll
    for (int s = 1; s < NS; ++s) { if (y == s) { ty1 = t1[s]; ty2 = t2[s]; } }

    float c = 0.5f * ((lse1 + ty1) + (lse2v + ty2));

    #pragma unroll
    for (int off = 32; off >= 1; off >>= 1) c += __shfl_down(c, off, 64);
    if ((row & 63) == 0) red[row >> 6] = c;
    __syncthreads();
    if (row == 0) {
        float tot = 0.f;
        #pragma unroll
        for (int i = 0; i < 16; ++i) tot += red[i];
        out[0] = tot * (1.0f / (float)NROW);
    }
}

extern "C" void kernel_launch(void* const* d_in, const int* in_sizes, int n_in,
                              void* d_out, int out_size, void* d_ws, size_t ws_size,
                              hipStream_t stream) {
    const float* supp  = (const float*)d_in[0];
    const float* query = (const float*)d_in[1];
    const int*   ys    = (const int*)d_in[2];
    float* out = (float*)d_out;

    float* t1w    = (float*)d_ws;                               // 5120
    float* t2w    = t1w + NROW * NS;                            // 5120
    float* suppSq = t2w + NROW * NS;                            // 640
    float* qssBuf = suppSq + NSROW;                             // KS*1024*16 = 65536
    float* dotBuf = qssBuf + (size_t)KS * NROW * 16;            // KS*1024*5*256 = 5.24M f32
    unsigned short* suppBf = (unsigned short*)(dotBuf + (size_t)KS * NROW * NS * 256);

    preproc_supp<<<NSROW / 4, 256, 0, stream>>>(supp, suppBf, suppSq);
    partial_gemm_kernel<<<NROW * KS, 320, 0, stream>>>(suppBf, query, dotBuf, qssBuf);
    dtw_kernel<<<NROW, 320, 0, stream>>>(dotBuf, qssBuf, suppSq, out + 1, t1w, t2w);
    loss_kernel<<<1, 1024, 0, stream>>>(t1w, t2w, ys, out);
}

// Round 8
// 307.383 us; speedup vs baseline: 1.2978x; 1.2978x over previous
//
#include <hip/hip_runtime.h>
#include <hip/hip_bf16.h>

#define NB   8
#define NS   5
#define NQ   128
#define TT   16
#define DD   2048
#define NROW 1024               // B*nq
#define NSROW (NB * NS * TT)    // 640 supp rows
#define KS   4                  // K-split factor (blocks per (b,q))
#define KSTEPS 16               // k-steps of 32 per slice (DD/32/KS)
#define LAMI 10.0f
#define LAMF 0.1f

typedef __attribute__((ext_vector_type(8))) short  short8;
typedef __attribute__((ext_vector_type(4))) float  float4v;

// pack two f32 -> bf16x2 (RNE)
static __device__ __forceinline__ unsigned int f2bf2(float x, float y) {
    union { float f; unsigned int u; } a, b; a.f = x; b.f = y;
    unsigned int ra = a.u + 0x7fffu + ((a.u >> 16) & 1u);
    unsigned int rb = b.u + 0x7fffu + ((b.u >> 16) & 1u);
    return (ra >> 16) | (rb & 0xffff0000u);
}

static __device__ __forceinline__ float lse2f(float x, float y) {
    float mx = fmaxf(x, y), mn = fminf(x, y);
    return mx + __logf(1.0f + __expf(mn - mx));
}

// supp only: f32 -> bf16 + row sum-of-squares. One wave per row (640 rows).
__global__ __launch_bounds__(256) void
preproc_supp(const float* __restrict__ supp, unsigned short* __restrict__ suppBf,
             float* __restrict__ suppSq)
{
    const int wave = threadIdx.x >> 6, lane = threadIdx.x & 63;
    const int row = blockIdx.x * 4 + wave;           // 0..639
    const float* src = supp + (size_t)row * DD;
    unsigned short* dst = suppBf + (size_t)row * DD;
    float ss = 0.f;
    #pragma unroll
    for (int i = 0; i < 8; ++i) {
        float4 v = *reinterpret_cast<const float4*>(src + i * 256 + lane * 4);
        uint2 pv = { f2bf2(v.x, v.y), f2bf2(v.z, v.w) };
        *reinterpret_cast<uint2*>(dst + i * 256 + lane * 4) = pv;
        ss += v.x * v.x + v.y * v.y + v.z * v.z + v.w * v.w;
    }
    #pragma unroll
    for (int off = 32; off >= 1; off >>= 1) ss += __shfl_xor(ss, off, 64);
    if (lane == 0) suppSq[row] = ss;
}

// ---- kernel B: partial GEMM, K split across blocks ----
// grid = NROW*KS; block (blk, ks) computes, for all 5 supports, the partial dot tile
// over K slice [ks*512, (ks+1)*512). Wave = support s. Hand-unrolled 4-step chunk
// double-buffer with literal indices. __launch_bounds__(320,2): allow ~128 VGPR so
// the 48-deep load pipeline actually lives in registers (R7's (320,4) forced 64 -> spill).

#define LOADSTEP(pre, slot, kstep)                                              \
    pre##q0[slot] = *reinterpret_cast<const float4*>(qp + (kstep) * 32);        \
    pre##q1[slot] = *reinterpret_cast<const float4*>(qp + (kstep) * 32 + 4);    \
    pre##a[slot]  = *reinterpret_cast<const short8*>(ap + (kstep) * 32);

#define PROCSTEP(pre, slot) {                                                   \
    float4 v0 = pre##q0[slot], v1 = pre##q1[slot];                              \
    union { short8 s8; unsigned int u[4]; } bu;                                 \
    bu.u[0] = f2bf2(v0.x, v0.y);                                                \
    bu.u[1] = f2bf2(v0.z, v0.w);                                                \
    bu.u[2] = f2bf2(v1.x, v1.y);                                                \
    bu.u[3] = f2bf2(v1.z, v1.w);                                                \
    qss += v0.x * v0.x + v0.y * v0.y + v0.z * v0.z + v0.w * v0.w               \
         + v1.x * v1.x + v1.y * v1.y + v1.z * v1.z + v1.w * v1.w;              \
    acc = __builtin_amdgcn_mfma_f32_16x16x32_bf16(pre##a[slot], bu.s8, acc, 0, 0, 0); }

__global__ __launch_bounds__(320, 2) void
partial_gemm_kernel(const unsigned short* __restrict__ suppBf, const float* __restrict__ query,
                    float* __restrict__ dotBuf, float* __restrict__ qssBuf)
{
    const int tid  = threadIdx.x;
    const int blk  = blockIdx.x >> 2;     // (b,q) 0..1023
    const int ks   = blockIdx.x & 3;      // K-slice 0..3
    const int wave = tid >> 6;            // 0..4 == s
    const int lane = tid & 63;
    const int fr   = lane & 15;
    const int quad = lane >> 4;

    const float* qp = query + ((size_t)(blk * TT + fr)) * DD + ks * (KSTEPS * 32) + quad * 8;
    const unsigned short* ap =
        suppBf + ((size_t)((blk >> 7) * NS + wave) * TT + fr) * DD + ks * (KSTEPS * 32) + quad * 8;

    float4 Aq0[4], Aq1[4], Bq0[4], Bq1[4];
    short8 Aa[4], Ba[4];
    float4v acc = {0.f, 0.f, 0.f, 0.f};
    float qss = 0.f;

    // chunk 0 -> A
    LOADSTEP(A, 0, 0)  LOADSTEP(A, 1, 1)  LOADSTEP(A, 2, 2)  LOADSTEP(A, 3, 3)
    // load chunk1 -> B, process A
    LOADSTEP(B, 0, 4)  LOADSTEP(B, 1, 5)  LOADSTEP(B, 2, 6)  LOADSTEP(B, 3, 7)
    PROCSTEP(A, 0) PROCSTEP(A, 1) PROCSTEP(A, 2) PROCSTEP(A, 3)
    // load chunk2 -> A, process B
    LOADSTEP(A, 0, 8)  LOADSTEP(A, 1, 9)  LOADSTEP(A, 2, 10) LOADSTEP(A, 3, 11)
    PROCSTEP(B, 0) PROCSTEP(B, 1) PROCSTEP(B, 2) PROCSTEP(B, 3)
    // load chunk3 -> B, process A
    LOADSTEP(B, 0, 12) LOADSTEP(B, 1, 13) LOADSTEP(B, 2, 14) LOADSTEP(B, 3, 15)
    PROCSTEP(A, 0) PROCSTEP(A, 1) PROCSTEP(A, 2) PROCSTEP(A, 3)
    // process B
    PROCSTEP(B, 0) PROCSTEP(B, 1) PROCSTEP(B, 2) PROCSTEP(B, 3)

    // store partial dot tile: dotBuf[(ks*1024+blk)*5+s][l][m], C-layout l=quad*4+r, m=fr
    float* dp = dotBuf + (((size_t)(ks * NROW + blk) * NS + wave) * 256);
    #pragma unroll
    for (int r = 0; r < 4; ++r)
        dp[(quad * 4 + r) * 16 + fr] = acc[r];

    // query sumsq partial for this slice (identical in all waves; wave 0 writes)
    qss += __shfl_xor(qss, 16, 64);
    qss += __shfl_xor(qss, 32, 64);
    if (wave == 0 && lane < 16)
        qssBuf[(size_t)(ks * NROW + blk) * 16 + lane] = qss;
}

// ---- kernel C: reduce partials, normalize, DTW ----
__global__ __launch_bounds__(320) void
dtw_kernel(const float* __restrict__ dotBuf, const float* __restrict__ qssBuf,
           const float* __restrict__ suppSq,
           float* __restrict__ out_tam, float* __restrict__ t1w, float* __restrict__ t2w)
{
    __shared__ float ssqS[80];
    __shared__ float ssqQ[16];
    __shared__ float distS[NS][TT][TT];
    __shared__ float tamv[16];

    const int tid  = threadIdx.x;
    const int blk  = blockIdx.x;
    const int wave = tid >> 6;            // 0..4 == s
    const int lane = tid & 63;
    const int fr   = lane & 15;
    const int quad = lane >> 4;

    if (tid < 80) ssqS[tid] = suppSq[(blk >> 7) * (NS * TT) + tid];
    if (tid >= 80 && tid < 96) {
        int m = tid - 80;
        float t = 0.f;
        #pragma unroll
        for (int k = 0; k < KS; ++k) t += qssBuf[(size_t)(k * NROW + blk) * 16 + m];
        ssqQ[m] = sqrtf(t);
    }

    float dot[4];
    {
        const float* dp0 = dotBuf + (((size_t)blk * NS + wave) * 256);
        #pragma unroll
        for (int r = 0; r < 4; ++r) {
            int off = (quad * 4 + r) * 16 + fr;
            float t = 0.f;
            #pragma unroll
            for (int k = 0; k < KS; ++k) t += dp0[(size_t)k * NROW * NS * 256 + off];
            dot[r] = t;
        }
    }
    __syncthreads();

    {
        float qn = ssqQ[fr];
        #pragma unroll
        for (int r = 0; r < 4; ++r) {
            int l = quad * 4 + r;
            float denom = fmaxf(sqrtf(ssqS[wave * 16 + l]) * qn, 1e-8f);
            distS[wave][l][fr] = 1.0f - dot[r] / denom;
        }
    }
    __syncthreads();

    // DTW: anti-diagonal wavefront; wave s, lanes 0..17 dir=0, 32..49 dir=1
    if ((lane & 31) <= 17) {
        const int g   = lane & 31;
        const int dir = lane >> 5;
        const int s   = wave;
        float val = 0.f, vprev = 0.f;
        #pragma unroll
        for (int t = 1; t <= 32; ++t) {
            float left = __shfl_up(val,   1, 32);
            float diag = __shfl_up(vprev, 1, 32);
            int l = t - g;
            if (g >= 1 && l >= 0 && l <= 15) {
                float d = 0.f;
                if (g <= 16) d = dir ? distS[s][15 - l][16 - g] : distS[s][l][g - 1];
                float nv;
                if (l == 0) {
                    nv = left + d;
                } else if (g == 1 || g == 17) {
                    nv = -LAMF * lse2f(lse2f(-diag * LAMI, -left * LAMI), -val * LAMI) + d;
                } else {
                    float lo2 = fminf(diag, left), hi2 = fmaxf(diag, left);
                    nv = lo2 - LAMF * __logf(1.0f + __expf((lo2 - hi2) * LAMI)) + d;
                }
                vprev = val; val = nv;
            }
        }
        if (g == 17) tamv[s * 2 + dir] = val;
    }
    __syncthreads();

    if (tid < NS) {
        float t1 = tamv[2 * tid], t2 = tamv[2 * tid + 1];
        int n = blk * NS + tid;
        t1w[n] = t1;
        t2w[n] = t2;
        out_tam[n] = 0.5f * (t1 + t2);
    }
}

__global__ __launch_bounds__(1024) void
loss_kernel(const float* __restrict__ t1w, const float* __restrict__ t2w,
            const int* __restrict__ ys, float* __restrict__ out)
{
    __shared__ float red[16];
    const int row = threadIdx.x;

    float t1[NS], t2[NS];
    #pragma unroll
    for (int s = 0; s < NS; ++s) { t1[s] = t1w[row * NS + s]; t2[s] = t2w[row * NS + s]; }
    const int y = ys[row];

    float mx1 = -t1[0], mx2 = -t2[0];
    #pragma unroll
    for (int s = 1; s < NS; ++s) { mx1 = fmaxf(mx1, -t1[s]); mx2 = fmaxf(mx2, -t2[s]); }
    float s1 = 0.f, s2 = 0.f;
    #pragma unroll
    for (int s = 0; s < NS; ++s) { s1 += __expf(-t1[s] - mx1); s2 += __expf(-t2[s] - mx2); }
    float lse1  = mx1 + __logf(s1);
    float lse2v = mx2 + __logf(s2);

    float ty1 = t1[0], ty2 = t2[0];
    #pragma unroll
    for (int s = 1; s < NS; ++s) { if (y == s) { ty1 = t1[s]; ty2 = t2[s]; } }

    float c = 0.5f * ((lse1 + ty1) + (lse2v + ty2));

    #pragma unroll
    for (int off = 32; off >= 1; off >>= 1) c += __shfl_down(c, off, 64);
    if ((row & 63) == 0) red[row >> 6] = c;
    __syncthreads();
    if (row == 0) {
        float tot = 0.f;
        #pragma unroll
        for (int i = 0; i < 16; ++i) tot += red[i];
        out[0] = tot * (1.0f / (float)NROW);
    }
}

extern "C" void kernel_launch(void* const* d_in, const int* in_sizes, int n_in,
                              void* d_out, int out_size, void* d_ws, size_t ws_size,
                              hipStream_t stream) {
    const float* supp  = (const float*)d_in[0];
    const float* query = (const float*)d_in[1];
    const int*   ys    = (const int*)d_in[2];
    float* out = (float*)d_out;

    float* t1w    = (float*)d_ws;                               // 5120
    float* t2w    = t1w + NROW * NS;                            // 5120
    float* suppSq = t2w + NROW * NS;                            // 640
    float* qssBuf = suppSq + NSROW;                             // KS*1024*16 = 65536
    float* dotBuf = qssBuf + (size_t)KS * NROW * 16;            // KS*1024*5*256 = 5.24M f32
    unsigned short* suppBf = (unsigned short*)(dotBuf + (size_t)KS * NROW * NS * 256);

    preproc_supp<<<NSROW / 4, 256, 0, stream>>>(supp, suppBf, suppSq);
    partial_gemm_kernel<<<NROW * KS, 320, 0, stream>>>(suppBf, query, dotBuf, qssBuf);
    dtw_kernel<<<NROW, 320, 0, stream>>>(dotBuf, qssBuf, suppSq, out + 1, t1w, t2w);
    loss_kernel<<<1, 1024, 0, stream>>>(t1w, t2w, ys, out);
}